// Round 10
// baseline (143.868 us; speedup 1.0000x reference)
//
#include <hip/hip_runtime.h>
#include <math.h>

#define NWAVE 64
#define DMODEL 128
#define N_FIXED 768
#define TILE 32
#define T_TILES 24       // 768/32
#define TPAIRS 300       // 24*25/2
#define NSLOT 25
#define K1_BLOCK 512     // 8 waves; wave wid owns rows [wid*4, wid*4+4)
#define K2_BLOCK 256
// ws layout: ws[((b*T_TILES + t)*NSLOT + slot)*TILE*DMODEL + row*DMODEL + col]
// tile t receives: non-diag J at slots {0..t-1}, I at slots {t..23}, diag-J at {24}
#define WS_FLOATS_PER_TILE (NSLOT * TILE * DMODEL)   // 102400
#define WS_FLOATS_PER_B   ((size_t)T_TILES * WS_FLOATS_PER_TILE)

// Symmetric tile-pair kernel, attempt 5. R7-R9 lessons baked in:
//  - col-major J: only jRc/jIc live per col -> ~45 VGPR, spill IMPOSSIBLE
//    (R7/R8/R9 all gambled on 64 live scalars and lost or couldn't verify)
//  - J flushed via 2 ds_add_f32 per col per wave (512/block total, staggered
//    start per wave -> negligible contention; NOT per-element like R6)
//  - 8 waves x 4 rows: 4800 waves / 1024 SIMDs -> 6.6% ceil-tail (vs 28%)
//  - LDS ~26KB -> >=4 blocks/CU resident, no block serialization
template <bool USE_WS>
__global__ __launch_bounds__(K1_BLOCK) void spatial_embed_pairs(
    const float* __restrict__ x,            // [B, N, 3]
    const unsigned char* __restrict__ mask, // [B, N] bool (0 = valid)
    float* __restrict__ out,                // used only when !USE_WS (pre-zeroed)
    float* __restrict__ ws,                 // used only when USE_WS
    int B, int N)
{
    __shared__ float xI[TILE][3], xJ[TILE][3];
    __shared__ float vI[TILE], vJ[TILE];
    __shared__ __align__(16) float2 pairT[TILE * TILE]; // [c][row] {r, ok/r}
    __shared__ float jaccR[TILE * NWAVE];               // [c][lane] planar
    __shared__ float jaccI[TILE * NWAVE];

    const int tid  = threadIdx.x;
    const int lane = tid & 63;
    const int wid  = tid >> 6;               // 0..7

    // decode (b, it, jt), it <= jt
    int tp = blockIdx.x % TPAIRS;
    const int b = blockIdx.x / TPAIRS;
    int it = 0;
    while (tp >= T_TILES - it) { tp -= T_TILES - it; ++it; }
    const int jt = it + tp;
    const bool diag = (it == jt);
    const int ibase = it * TILE, jbase = jt * TILE;

    // ---- phase 0: stage coords + validity; zero jacc ----
    if (tid < TILE) {
        const int g = b * N + ibase + tid;
        xI[tid][0] = x[g * 3 + 0]; xI[tid][1] = x[g * 3 + 1]; xI[tid][2] = x[g * 3 + 2];
        vI[tid] = (mask[g] == 0) ? 1.0f : 0.0f;
    } else if (tid < 2 * TILE) {
        const int r = tid - TILE;
        const int g = b * N + jbase + r;
        xJ[r][0] = x[g * 3 + 0]; xJ[r][1] = x[g * 3 + 1]; xJ[r][2] = x[g * 3 + 2];
        vJ[r] = (mask[g] == 0) ? 1.0f : 0.0f;
    }
    for (int k = tid; k < TILE * NWAVE; k += K1_BLOCK) {
        jaccR[k] = 0.0f;
        jaccI[k] = 0.0f;
    }
    __syncthreads();

    // ---- phase 1: r-tile (TRANSPOSED: [c][row]) + fused validity ----
    for (int p = tid; p < TILE * TILE; p += K1_BLOCK) {
        const int c = p >> 5, a = p & (TILE - 1);
        const float dx = xI[a][0] - xJ[c][0];
        const float dy = xI[a][1] - xJ[c][1];
        const float dz = xI[a][2] - xJ[c][2];
        const float d2 = fmaf(dx, dx, fmaf(dy, dy, fmaf(dz, dz, 1e-6f)));
        const float irs = rsqrtf(d2);
        float ok = vI[a] * vJ[c];
        if (diag && a >= c) ok = 0.0f;       // diag: strictly upper (a<c) only
        pairT[p] = make_float2(d2 * irs, ok * irs);   // {r, ok/r}
    }
    __syncthreads();

    // ---- phase 2: col-major accumulation ----
    const float invlam = 0.5f * exp2f((float)lane * -0.07371200301229721f);
    const int r0 = wid * 4;

    float aR0 = 0.f, aI0 = 0.f, aR1 = 0.f, aI1 = 0.f;
    float aR2 = 0.f, aI2 = 0.f, aR3 = 0.f, aI3 = 0.f;

    #pragma unroll 8
    for (int cc = 0; cc < TILE; ++cc) {
        const int c = (cc + wid * 4) & (TILE - 1);   // stagger waves across cols
        const float4 q01 = *(const float4*)&pairT[c * TILE + r0];      // rows r0,r0+1
        const float4 q23 = *(const float4*)&pairT[c * TILE + r0 + 2];  // rows r0+2,r0+3
        float jRc = 0.0f, jIc = 0.0f;
        {
            const float rev = q01.x * invlam;
            const float sn = __builtin_amdgcn_sinf(rev);
            const float cs = __builtin_amdgcn_cosf(rev);
            aR0 = fmaf(cs, q01.y, aR0);  aI0 = fmaf(sn, q01.y, aI0);
            jRc = fmaf(cs, q01.y, jRc);  jIc = fmaf(sn, q01.y, jIc);
        }
        {
            const float rev = q01.z * invlam;
            const float sn = __builtin_amdgcn_sinf(rev);
            const float cs = __builtin_amdgcn_cosf(rev);
            aR1 = fmaf(cs, q01.w, aR1);  aI1 = fmaf(sn, q01.w, aI1);
            jRc = fmaf(cs, q01.w, jRc);  jIc = fmaf(sn, q01.w, jIc);
        }
        {
            const float rev = q23.x * invlam;
            const float sn = __builtin_amdgcn_sinf(rev);
            const float cs = __builtin_amdgcn_cosf(rev);
            aR2 = fmaf(cs, q23.y, aR2);  aI2 = fmaf(sn, q23.y, aI2);
            jRc = fmaf(cs, q23.y, jRc);  jIc = fmaf(sn, q23.y, jIc);
        }
        {
            const float rev = q23.z * invlam;
            const float sn = __builtin_amdgcn_sinf(rev);
            const float cs = __builtin_amdgcn_cosf(rev);
            aR3 = fmaf(cs, q23.w, aR3);  aI3 = fmaf(sn, q23.w, aI3);
            jRc = fmaf(cs, q23.w, jRc);  jIc = fmaf(sn, q23.w, jIc);
        }
        // J-side: one LDS float-atomic pair per col per wave (planar -> 2-way banks, free)
        atomicAdd(&jaccR[c * NWAVE + lane], jRc);
        atomicAdd(&jaccI[c * NWAVE + lane], jIc);
    }

    // ---- I-side flush (rows disjoint per wave) ----
    if constexpr (USE_WS) {
        float2* dst = (float2*)(ws +
            (((size_t)(b * T_TILES + it) * NSLOT + jt) * TILE + r0) * DMODEL);
        dst[0 * 64 + lane] = make_float2(aR0, aI0);
        dst[1 * 64 + lane] = make_float2(aR1, aI1);
        dst[2 * 64 + lane] = make_float2(aR2, aI2);
        dst[3 * 64 + lane] = make_float2(aR3, aI3);
    } else {
        atomicAdd(&out[(b * N + ibase + r0 + 0) * DMODEL + 2 * lane],     aR0);
        atomicAdd(&out[(b * N + ibase + r0 + 0) * DMODEL + 2 * lane + 1], aI0);
        atomicAdd(&out[(b * N + ibase + r0 + 1) * DMODEL + 2 * lane],     aR1);
        atomicAdd(&out[(b * N + ibase + r0 + 1) * DMODEL + 2 * lane + 1], aI1);
        atomicAdd(&out[(b * N + ibase + r0 + 2) * DMODEL + 2 * lane],     aR2);
        atomicAdd(&out[(b * N + ibase + r0 + 2) * DMODEL + 2 * lane + 1], aI2);
        atomicAdd(&out[(b * N + ibase + r0 + 3) * DMODEL + 2 * lane],     aR3);
        atomicAdd(&out[(b * N + ibase + r0 + 3) * DMODEL + 2 * lane + 1], aI3);
    }

    __syncthreads();

    // ---- J-side flush ----
    const int slotJ = diag ? (NSLOT - 1) : it;
    if constexpr (USE_WS) {
        float2* dst = (float2*)(ws +
            ((size_t)(b * T_TILES + jt) * NSLOT + slotJ) * TILE * DMODEL);
        for (int k = tid; k < TILE * NWAVE; k += K1_BLOCK)
            dst[k] = make_float2(jaccR[k], jaccI[k]);   // k = c*64 + w
    } else {
        for (int k = tid; k < TILE * NWAVE; k += K1_BLOCK) {
            const int c = k >> 6, w = k & 63;
            const int grow = b * N + jbase + c;
            atomicAdd(&out[grow * DMODEL + 2 * w],     jaccR[k]);
            atomicAdd(&out[grow * DMODEL + 2 * w + 1], jaccI[k]);
        }
    }
}

// Sum the 25 slots per output tile. grid = B*T_TILES*4; block handles 1024
// consecutive floats (256 thr x float4). Fixed order -> deterministic.
__global__ __launch_bounds__(K2_BLOCK) void reduce_ws(
    const float* __restrict__ ws, float* __restrict__ out)
{
    const int blk   = blockIdx.x;
    const int chunk = blk & 3;
    const int bt    = blk >> 2;            // b*T_TILES + t
    const int e4    = chunk * 256 + threadIdx.x;
    const float4* base = (const float4*)(ws + (size_t)bt * WS_FLOATS_PER_TILE) + e4;
    float4 s = make_float4(0.f, 0.f, 0.f, 0.f);
    #pragma unroll
    for (int sl = 0; sl < NSLOT; ++sl) {
        const float4 v = base[sl * (TILE * DMODEL / 4)];
        s.x += v.x; s.y += v.y; s.z += v.z; s.w += v.w;
    }
    ((float4*)(out + (size_t)bt * TILE * DMODEL))[e4] = s;
}

extern "C" void kernel_launch(void* const* d_in, const int* in_sizes, int n_in,
                              void* d_out, int out_size, void* d_ws, size_t ws_size,
                              hipStream_t stream) {
    const float* x = (const float*)d_in[0];
    const unsigned char* mask = (const unsigned char*)d_in[1];
    float* out = (float*)d_out;
    float* ws  = (float*)d_ws;

    const int N = N_FIXED;
    const int BN = in_sizes[1];              // B*N
    const int B = BN / N;

    const size_t ws_need = (size_t)B * WS_FLOATS_PER_B * sizeof(float);
    if (ws_size >= ws_need) {
        spatial_embed_pairs<true><<<dim3(B * TPAIRS), dim3(K1_BLOCK), 0, stream>>>(
            x, mask, out, ws, B, N);
        reduce_ws<<<dim3(B * T_TILES * 4), dim3(K2_BLOCK), 0, stream>>>(ws, out);
    } else {
        hipMemsetAsync(d_out, 0, (size_t)out_size * sizeof(float), stream);
        spatial_embed_pairs<false><<<dim3(B * TPAIRS), dim3(K1_BLOCK), 0, stream>>>(
            x, mask, out, ws, B, N);
    }
}

// Round 11
// 24.862 us; speedup vs baseline: 5.7867x; 5.7867x over previous
//
#include <hip/hip_runtime.h>
#include <math.h>

#define NWAVE 64
#define DMODEL 128
#define BLOCK 256
#define N_FIXED 768

// R5 structure (best: 20.9us) + hybrid trans/poly split.
// R5 was trans-unit-bound (v_sin/v_cos saturated, ~15.4us of trans work,
// VALU issue ~idle); R4 was the dual (pure-poly, 33.9us issue-bound, trans
// idle). These are separate HW resources: route 3/4 of elements through
// v_sin/v_cos and 1/4 through the R4 Taylor polynomial so co-resident waves
// fill both pipes. Model: max(0.75*15.4, 0.75*8 + 0.25*33.9) ~= 14.5us.
__global__ __launch_bounds__(BLOCK) void spatial_embed_kernel(
    const float* __restrict__ x,            // [B, N, 3]
    const unsigned char* __restrict__ mask, // [B, N] bool (0 = valid)
    float* __restrict__ out,                // [B, N, DMODEL]
    int B, int N)
{
    const int bi  = blockIdx.x;              // b*N + i
    const int b   = bi / N;
    const int i   = bi - b * N;
    const int tid = threadIdx.x;

    __shared__ __align__(16) float s_r[N_FIXED];
    __shared__ __align__(16) float s_invr[N_FIXED];
    __shared__ float2 partial[BLOCK];

    const float xi = x[bi * 3 + 0];
    const float yi = x[bi * 3 + 1];
    const float zi = x[bi * 3 + 2];

    // ---- phase 1: distances into LDS ----
    for (int j = tid; j < N; j += BLOCK) {
        const float dx = xi - x[(b * N + j) * 3 + 0];
        const float dy = yi - x[(b * N + j) * 3 + 1];
        const float dz = zi - x[(b * N + j) * 3 + 2];
        const float r  = sqrtf(fmaf(dx, dx, fmaf(dy, dy, fmaf(dz, dz, 1e-6f))));
        const bool valid = (j != i) && (mask[b * N + j] == 0);
        s_r[j]    = r;
        s_invr[j] = valid ? (1.0f / r) : 0.0f;
    }
    __syncthreads();

    // ---- phase 2 ----
    const int w     = tid & (NWAVE - 1);
    const int chunk = tid >> 6;              // 0..3

    // rev = r / lambda_w (v_sin/v_cos take revolutions); 1/lambda = 0.5*25^(-w/63)
    const float invlam = 0.5f * exp2f((float)w * -0.07371200301229721f);

    float aR0 = 0.f, aI0 = 0.f, aR1 = 0.f, aI1 = 0.f;

    const int nq = (N_FIXED / 4) / 4;        // 48 quads per wave-chunk
    const float4* r4 = (const float4*)s_r;
    const float4* v4 = (const float4*)s_invr;
    const int q0 = chunk * nq;

    // Taylor poly sin/cos of 2*pi*rev (same coeffs as R3/R4, proven absmax):
    auto poly_sincos = [](float rev, float& sn, float& cs) {
        const float t = rev - rintf(rev);    // t in [-1/2, 1/2]
        const float u = t * t;
        float sh = fmaf(-15.094643f, u, 42.058693f);
        sh = fmaf(sh, u, -76.705860f);
        sh = fmaf(sh, u, 81.605249f);
        sh = fmaf(sh, u, -41.341702f);
        sh = fmaf(sh, u, 6.2831853f);
        float ch = fmaf(7.9035364f, u, -26.426256f);
        ch = fmaf(ch, u, 60.244641f);
        ch = fmaf(ch, u, -85.456817f);
        ch = fmaf(ch, u, 64.939394f);
        ch = fmaf(ch, u, -19.739209f);
        sn = t * sh;
        cs = fmaf(u, ch, 1.0f);
    };

    // 4-element body: elements x,y,z via HW trans, element w via polynomial.
    auto body = [&](const float4 rr, const float4 vv) {
        const float rev0 = rr.x * invlam;
        const float rev1 = rr.y * invlam;
        const float rev2 = rr.z * invlam;
        const float rev3 = rr.w * invlam;
        // poly path first: its 16-op VALU chain fills issue slots while the
        // three trans pairs below grind the trans unit.
        float s3, c3;
        poly_sincos(rev3, s3, c3);
        const float s0 = __builtin_amdgcn_sinf(rev0);
        const float c0 = __builtin_amdgcn_cosf(rev0);
        const float s1 = __builtin_amdgcn_sinf(rev1);
        const float c1 = __builtin_amdgcn_cosf(rev1);
        const float s2 = __builtin_amdgcn_sinf(rev2);
        const float c2 = __builtin_amdgcn_cosf(rev2);
        aR0 = fmaf(c0, vv.x, aR0);  aI0 = fmaf(s0, vv.x, aI0);
        aR1 = fmaf(c1, vv.y, aR1);  aI1 = fmaf(s1, vv.y, aI1);
        aR0 = fmaf(c2, vv.z, aR0);  aI0 = fmaf(s2, vv.z, aI0);
        aR1 = fmaf(c3, vv.w, aR1);  aI1 = fmaf(s3, vv.w, aI1);
    };

    // software pipeline: prefetch quad q+1 into regs before computing quad q
    float4 rr = r4[q0];
    float4 vv = v4[q0];
    #pragma unroll 4
    for (int q = q0; q < q0 + nq - 1; ++q) {
        const float4 rrn = r4[q + 1];        // issue loads early
        const float4 vvn = v4[q + 1];
        body(rr, vv);                        // compute overlaps the loads
        rr = rrn;
        vv = vvn;
    }
    body(rr, vv);                            // epilogue (last quad)

    partial[tid] = make_float2(aR0 + aR1, aI0 + aI1);
    __syncthreads();

    // ---- reduce 4 chunks, store interleaved (re, im) ----
    if (tid < NWAVE) {
        const float2 p0 = partial[tid];
        const float2 p1 = partial[tid + 64];
        const float2 p2 = partial[tid + 128];
        const float2 p3 = partial[tid + 192];
        float re = (p0.x + p1.x) + (p2.x + p3.x);
        float im = (p0.y + p1.y) + (p2.y + p3.y);
        if (mask[bi] != 0) { re = 0.0f; im = 0.0f; }
        out[bi * DMODEL + 2 * tid + 0] = re;
        out[bi * DMODEL + 2 * tid + 1] = im;
    }
}

extern "C" void kernel_launch(void* const* d_in, const int* in_sizes, int n_in,
                              void* d_out, int out_size, void* d_ws, size_t ws_size,
                              hipStream_t stream) {
    const float* x = (const float*)d_in[0];
    const unsigned char* mask = (const unsigned char*)d_in[1];
    float* out = (float*)d_out;

    const int N = N_FIXED;
    const int BN = in_sizes[1];              // B*N
    const int B = BN / N;

    spatial_embed_kernel<<<dim3(BN), dim3(BLOCK), 0, stream>>>(x, mask, out, B, N);
}

// Round 12
// 20.998 us; speedup vs baseline: 6.8515x; 1.1840x over previous
//
#include <hip/hip_runtime.h>
#include <math.h>

#define NWAVE 64
#define DMODEL 128
#define BLOCK 256
#define N_FIXED 768

// FINAL (= R5, best measured: 20.9us). One block per (b,i) query row.
// Phase 1: distances -> LDS (SoA). Phase 2: lane = wavelength w, wave =
// j-chunk, HW v_sin/v_cos in revolutions, register prefetch of the next
// quad to hide ds_read latency.
//
// Why this is the floor (validated issue-port model, R2/R4/R5/R11 fits):
// the SIMD's single issue port is the bottleneck; per element we pay
// 2 trans (~16 cyc each) + rev-mul + 2 acc-FMA (~3 cyc each) + amortized
// ds_read ~= 44 port-cyc; measured 43.5. Hybrid trans/poly (R11) and
// symmetry (R6-R10) both lose: mixing can't reduce total port-cycles, and
// the symmetric scatter's distribution overhead (LDS atomics / extra
// kernel / block quantization) exceeds the 8us of trans it saves.
__global__ __launch_bounds__(BLOCK) void spatial_embed_kernel(
    const float* __restrict__ x,            // [B, N, 3]
    const unsigned char* __restrict__ mask, // [B, N] bool (0 = valid)
    float* __restrict__ out,                // [B, N, DMODEL]
    int B, int N)
{
    const int bi  = blockIdx.x;              // b*N + i
    const int b   = bi / N;
    const int i   = bi - b * N;
    const int tid = threadIdx.x;

    __shared__ __align__(16) float s_r[N_FIXED];
    __shared__ __align__(16) float s_invr[N_FIXED];
    __shared__ float2 partial[BLOCK];

    const float xi = x[bi * 3 + 0];
    const float yi = x[bi * 3 + 1];
    const float zi = x[bi * 3 + 2];

    // ---- phase 1: distances into LDS ----
    for (int j = tid; j < N; j += BLOCK) {
        const float dx = xi - x[(b * N + j) * 3 + 0];
        const float dy = yi - x[(b * N + j) * 3 + 1];
        const float dz = zi - x[(b * N + j) * 3 + 2];
        const float r  = sqrtf(fmaf(dx, dx, fmaf(dy, dy, fmaf(dz, dz, 1e-6f))));
        const bool valid = (j != i) && (mask[b * N + j] == 0);
        s_r[j]    = r;
        s_invr[j] = valid ? (1.0f / r) : 0.0f;
    }
    __syncthreads();

    // ---- phase 2 ----
    const int w     = tid & (NWAVE - 1);
    const int chunk = tid >> 6;              // 0..3

    // rev = r / lambda_w (v_sin/v_cos take revolutions); 1/lambda = 0.5*25^(-w/63)
    const float invlam = 0.5f * exp2f((float)w * -0.07371200301229721f);

    float aR0 = 0.f, aI0 = 0.f, aR1 = 0.f, aI1 = 0.f;

    const int nq = (N_FIXED / 4) / 4;        // 48 quads per wave-chunk
    const float4* r4 = (const float4*)s_r;
    const float4* v4 = (const float4*)s_invr;
    const int q0 = chunk * nq;

    // 4-element body on registers (2 independent acc pairs for ILP)
    auto body = [&](const float4 rr, const float4 vv) {
        const float rev0 = rr.x * invlam;
        const float rev1 = rr.y * invlam;
        const float rev2 = rr.z * invlam;
        const float rev3 = rr.w * invlam;
        const float s0 = __builtin_amdgcn_sinf(rev0);
        const float c0 = __builtin_amdgcn_cosf(rev0);
        const float s1 = __builtin_amdgcn_sinf(rev1);
        const float c1 = __builtin_amdgcn_cosf(rev1);
        const float s2 = __builtin_amdgcn_sinf(rev2);
        const float c2 = __builtin_amdgcn_cosf(rev2);
        const float s3 = __builtin_amdgcn_sinf(rev3);
        const float c3 = __builtin_amdgcn_cosf(rev3);
        aR0 = fmaf(c0, vv.x, aR0);  aI0 = fmaf(s0, vv.x, aI0);
        aR1 = fmaf(c1, vv.y, aR1);  aI1 = fmaf(s1, vv.y, aI1);
        aR0 = fmaf(c2, vv.z, aR0);  aI0 = fmaf(s2, vv.z, aI0);
        aR1 = fmaf(c3, vv.w, aR1);  aI1 = fmaf(s3, vv.w, aI1);
    };

    // software pipeline: prefetch quad q+1 into regs before computing quad q
    float4 rr = r4[q0];
    float4 vv = v4[q0];
    #pragma unroll 4
    for (int q = q0; q < q0 + nq - 1; ++q) {
        const float4 rrn = r4[q + 1];        // issue loads early
        const float4 vvn = v4[q + 1];
        body(rr, vv);                        // compute overlaps the loads
        rr = rrn;
        vv = vvn;
    }
    body(rr, vv);                            // epilogue (last quad)

    partial[tid] = make_float2(aR0 + aR1, aI0 + aI1);
    __syncthreads();

    // ---- reduce 4 chunks, store interleaved (re, im) ----
    if (tid < NWAVE) {
        const float2 p0 = partial[tid];
        const float2 p1 = partial[tid + 64];
        const float2 p2 = partial[tid + 128];
        const float2 p3 = partial[tid + 192];
        float re = (p0.x + p1.x) + (p2.x + p3.x);
        float im = (p0.y + p1.y) + (p2.y + p3.y);
        if (mask[bi] != 0) { re = 0.0f; im = 0.0f; }
        out[bi * DMODEL + 2 * tid + 0] = re;
        out[bi * DMODEL + 2 * tid + 1] = im;
    }
}

extern "C" void kernel_launch(void* const* d_in, const int* in_sizes, int n_in,
                              void* d_out, int out_size, void* d_ws, size_t ws_size,
                              hipStream_t stream) {
    const float* x = (const float*)d_in[0];
    const unsigned char* mask = (const unsigned char*)d_in[1];
    float* out = (float*)d_out;

    const int N = N_FIXED;
    const int BN = in_sizes[1];              // B*N
    const int B = BN / N;

    spatial_embed_kernel<<<dim3(BN), dim3(BLOCK), 0, stream>>>(x, mask, out, B, N);
}